// Round 1
// baseline (378.512 us; speedup 1.0000x reference)
//
#include <hip/hip_runtime.h>
#include <hip/hip_bf16.h>
#include <hip/hip_cooperative_groups.h>

namespace cg = cooperative_groups;

#define B_DIM 32
#define N_IN 1000000
#define N_OUT 500000
#define NTILES_T (N_IN / 64)           // 15625 transpose tiles (64 cols each)
#define NTILES_G ((N_OUT + 63) / 64)   // 7813 gather tiles (64 o's each)

typedef float nfloat4 __attribute__((ext_vector_type(4)));

__device__ __forceinline__ unsigned int f32_to_bf16_rne(float f) {
    unsigned int u = __float_as_uint(f);
    unsigned int rounding = 0x7fffu + ((u >> 16) & 1u);
    return (u + rounding) >> 16;   // low 16 bits = bf16
}

// ---- Phase-1 body: transpose+downconvert one 64-column tile ----------------
__device__ __forceinline__ void transpose_tile_body(
    const float* __restrict__ x, unsigned short* __restrict__ xT,
    unsigned int (*tile)[17], const int t, const int tb)
{
    const int qi = t & 15;       // float4-column 0..15 (fast -> coalesced)
    const int p  = t >> 4;       // b-pair 0..15
    const int i0 = tb * 64;

    const float* r0 = x + (size_t)(2 * p)     * N_IN + i0 + qi * 4;
    const float* r1 = x + (size_t)(2 * p + 1) * N_IN + i0 + qi * 4;
    const nfloat4 va = __builtin_nontemporal_load((const nfloat4*)r0);
    const nfloat4 vb = __builtin_nontemporal_load((const nfloat4*)r1);

    tile[qi * 4 + 0][p] = f32_to_bf16_rne(va.x) | (f32_to_bf16_rne(vb.x) << 16);
    tile[qi * 4 + 1][p] = f32_to_bf16_rne(va.y) | (f32_to_bf16_rne(vb.y) << 16);
    tile[qi * 4 + 2][p] = f32_to_bf16_rne(va.z) | (f32_to_bf16_rne(vb.z) << 16);
    tile[qi * 4 + 3][p] = f32_to_bf16_rne(va.w) | (f32_to_bf16_rne(vb.w) << 16);
    __syncthreads();

    const int ii = t >> 2;       // 0..63
    const int gq = t & 3;        // 0..3
    uint4 pk;
    pk.x = tile[ii][gq * 4 + 0];
    pk.y = tile[ii][gq * 4 + 1];
    pk.z = tile[ii][gq * 4 + 2];
    pk.w = tile[ii][gq * 4 + 3];
    *(uint4*)((char*)xT + (size_t)(i0 + ii) * 64 + gq * 16) = pk;
}

// ---- Phase-2 body: cooperative gather, 4 lanes share one 64B xT row --------
__device__ __forceinline__ void gather_tile_body(
    const unsigned short* __restrict__ xT, const float* __restrict__ w,
    const int* __restrict__ idx, float* __restrict__ out,
    const int t, const int ob)
{
    const int g = t >> 2;                   // group 0..63 -> one o
    const int l = t & 3;                    // 16B chunk within 64B row
    const int o = ob * 64 + g;
    if (o >= N_OUT) return;

    const int base = 3 * o;
    const int   i0 = __builtin_nontemporal_load(idx + base + 0);
    const int   i1 = __builtin_nontemporal_load(idx + base + 1);
    const int   i2 = __builtin_nontemporal_load(idx + base + 2);
    const float w0 = __builtin_nontemporal_load(w + base + 0);
    const float w1 = __builtin_nontemporal_load(w + base + 1);
    const float w2 = __builtin_nontemporal_load(w + base + 2);

    const uint4 v0 = *(const uint4*)(xT + (size_t)i0 * B_DIM + l * 8);
    const uint4 v1 = *(const uint4*)(xT + (size_t)i1 * B_DIM + l * 8);
    const uint4 v2 = *(const uint4*)(xT + (size_t)i2 * B_DIM + l * 8);

    float acc[8];
#pragma unroll
    for (int j = 0; j < 8; ++j) acc[j] = 0.0f;

    const unsigned int u0[4] = {v0.x, v0.y, v0.z, v0.w};
    const unsigned int u1[4] = {v1.x, v1.y, v1.z, v1.w};
    const unsigned int u2[4] = {v2.x, v2.y, v2.z, v2.w};
#pragma unroll
    for (int m = 0; m < 4; ++m) {
        float a = acc[2 * m], c = acc[2 * m + 1];
        a = fmaf(w0, __uint_as_float(u0[m] << 16), a);
        c = fmaf(w0, __uint_as_float(u0[m] & 0xffff0000u), c);
        a = fmaf(w1, __uint_as_float(u1[m] << 16), a);
        c = fmaf(w1, __uint_as_float(u1[m] & 0xffff0000u), c);
        a = fmaf(w2, __uint_as_float(u2[m] << 16), a);
        c = fmaf(w2, __uint_as_float(u2[m] & 0xffff0000u), c);
        acc[2 * m] = a; acc[2 * m + 1] = c;
    }

    float* obase = out + (size_t)(8 * l) * N_OUT + o;
#pragma unroll
    for (int j = 0; j < 8; ++j) {
        __builtin_nontemporal_store(acc[j], obase + (size_t)j * N_OUT);
    }
}

// ---- Fused cooperative kernel: transpose -> grid.sync -> gather ------------
// __launch_bounds__(256, 8): cap VGPR at 64 so 8 blocks/CU (32 waves/CU) stay
// co-resident -> 2048-block cooperative grid = full-device occupancy.
__global__ __launch_bounds__(256, 8) void fused_kernel(
    const float* __restrict__ x, const float* __restrict__ w,
    const int* __restrict__ idx, float* __restrict__ out,
    unsigned short* __restrict__ xT)
{
    __shared__ unsigned int tile[64][17];
    const int t = threadIdx.x;

    {   // contiguous chunking: each block owns ~8 consecutive tiles
        const int tpb = (NTILES_T + gridDim.x - 1) / gridDim.x;
        const int ts  = blockIdx.x * tpb;
        const int te  = (ts + tpb < NTILES_T) ? (ts + tpb) : NTILES_T;
        for (int tb = ts; tb < te; ++tb) {
            transpose_tile_body(x, xT, tile, t, tb);
            __syncthreads();     // protect LDS tile reuse
        }
    }

    cg::this_grid().sync();      // agent-scope fence: xT visible across XCDs

    {
        const int gpb = (NTILES_G + gridDim.x - 1) / gridDim.x;
        const int os  = blockIdx.x * gpb;
        const int oe  = (os + gpb < NTILES_G) ? (os + gpb) : NTILES_G;
        for (int ob = os; ob < oe; ++ob) {
            gather_tile_body(xT, w, idx, out, t, ob);
        }
    }
}

// ---- Fallback kernels (identical to previous round) ------------------------
__global__ __launch_bounds__(256) void transpose_bf16_kernel(
    const float* __restrict__ x, unsigned short* __restrict__ xT)
{
    __shared__ unsigned int tile[64][17];
    transpose_tile_body(x, xT, tile, threadIdx.x, blockIdx.x);
}

__global__ __launch_bounds__(256) void gather_bf16_v2_kernel(
    const unsigned short* __restrict__ xT, const float* __restrict__ w,
    const int* __restrict__ idx, float* __restrict__ out)
{
    gather_tile_body(xT, w, idx, out, threadIdx.x, blockIdx.x);
}

__global__ __launch_bounds__(256) void direct_kernel(
    const float* __restrict__ x, const float* __restrict__ w,
    const int* __restrict__ idx, float* __restrict__ out)
{
    const int o = blockIdx.x * blockDim.x + threadIdx.x;
    if (o >= N_OUT) return;
    const int base = 3 * o;
    const int i0 = idx[base + 0], i1 = idx[base + 1], i2 = idx[base + 2];
    const float w0 = w[base + 0], w1 = w[base + 1], w2 = w[base + 2];
#pragma unroll 4
    for (int b = 0; b < B_DIM; ++b) {
        const float* __restrict__ xr = x + (size_t)b * N_IN;
        float acc = w0 * xr[i0];
        acc = fmaf(w1, xr[i1], acc);
        acc = fmaf(w2, xr[i2], acc);
        out[(size_t)b * N_OUT + o] = acc;
    }
}

extern "C" void kernel_launch(void* const* d_in, const int* in_sizes, int n_in,
                              void* d_out, int out_size, void* d_ws, size_t ws_size,
                              hipStream_t stream) {
    const float* x   = (const float*)d_in[0];
    const float* w   = (const float*)d_in[1];
    const int*   idx = (const int*)d_in[2];
    float* out = (float*)d_out;

    const size_t xt_bytes = (size_t)N_IN * B_DIM * sizeof(unsigned short); // 64 MB

    if (ws_size >= xt_bytes) {
        unsigned short* xT = (unsigned short*)d_ws;

        // Determine co-resident cooperative grid once (host-side, capture-safe).
        static int coop_grid = -2;
        if (coop_grid == -2) {
            int nb = 0;
            if (hipOccupancyMaxActiveBlocksPerMultiprocessor(
                    &nb, fused_kernel, 256, 0) == hipSuccess && nb > 0) {
                long g = (long)nb * 256;        // 256 CUs on MI355X
                if (g > 2048) g = 2048;
                coop_grid = (int)g;
            } else {
                coop_grid = 0;
            }
        }

        bool done = false;
        if (coop_grid > 0) {
            void* args[] = {(void*)&x, (void*)&w, (void*)&idx, (void*)&out, (void*)&xT};
            hipError_t e = hipLaunchCooperativeKernel(
                fused_kernel, dim3(coop_grid), dim3(256), args, 0, stream);
            if (e == hipSuccess) {
                done = true;
            } else {
                coop_grid = 0;   // never retry; fall back permanently
            }
        }
        if (!done) {
            transpose_bf16_kernel<<<N_IN / 64, 256, 0, stream>>>(x, xT);
            gather_bf16_v2_kernel<<<NTILES_G, 256, 0, stream>>>(xT, w, idx, out);
        }
    } else {
        const int blocks = (N_OUT + 255) / 256;
        direct_kernel<<<blocks, 256, 0, stream>>>(x, w, idx, out);
    }
}

// Round 2
// 246.506 us; speedup vs baseline: 1.5355x; 1.5355x over previous
//
#include <hip/hip_runtime.h>
#include <hip/hip_bf16.h>

#define B_DIM 32
#define N_IN 1000000
#define N_OUT 500000

typedef float nfloat4 __attribute__((ext_vector_type(4)));

__device__ __forceinline__ unsigned int f32_to_bf16_rne(float f) {
    unsigned int u = __float_as_uint(f);
    unsigned int rounding = 0x7fffu + ((u >> 16) & 1u);
    return (u + rounding) >> 16;   // low 16 bits = bf16
}

// ---------- Kernel 1: transpose+downconvert x (B,N_IN) f32 -> xT (N_IN,B) bf16 ----
// (unchanged from the verified 248 us round-0 version)
__global__ __launch_bounds__(256) void transpose_bf16_kernel(
    const float* __restrict__ x, unsigned short* __restrict__ xT)
{
    __shared__ unsigned int tile[64][17];   // [ii][b-pair], pad 17 -> <=2-way banks
    const int t  = threadIdx.x;
    const int i0 = blockIdx.x * 64;

    const int qi = t & 15;       // float4-column 0..15 (fast -> coalesced)
    const int p  = t >> 4;       // b-pair 0..15

    const float* r0 = x + (size_t)(2 * p)     * N_IN + i0 + qi * 4;
    const float* r1 = x + (size_t)(2 * p + 1) * N_IN + i0 + qi * 4;
    const nfloat4 va = __builtin_nontemporal_load((const nfloat4*)r0);
    const nfloat4 vb = __builtin_nontemporal_load((const nfloat4*)r1);

    tile[qi * 4 + 0][p] = f32_to_bf16_rne(va.x) | (f32_to_bf16_rne(vb.x) << 16);
    tile[qi * 4 + 1][p] = f32_to_bf16_rne(va.y) | (f32_to_bf16_rne(vb.y) << 16);
    tile[qi * 4 + 2][p] = f32_to_bf16_rne(va.z) | (f32_to_bf16_rne(vb.z) << 16);
    tile[qi * 4 + 3][p] = f32_to_bf16_rne(va.w) | (f32_to_bf16_rne(vb.w) << 16);
    __syncthreads();

    const int ii = t >> 2;       // 0..63
    const int g  = t & 3;        // 0..3
    uint4 pk;
    pk.x = tile[ii][g * 4 + 0];
    pk.y = tile[ii][g * 4 + 1];
    pk.z = tile[ii][g * 4 + 2];
    pk.w = tile[ii][g * 4 + 3];
    // regular (cached) store: gather re-reads xT; L3 retention is worth it
    *(uint4*)((char*)xT + (size_t)(i0 + ii) * 64 + g * 16) = pk;
}

// ---------- Kernel 2 v3: cooperative gather, 2 o's per 4-lane group ----------
// Group g handles o_a = base+g and o_b = base+64+g (both halves keep 16
// consecutive o's per wave-store-instr -> 64B store segments preserved).
// All 6 xT row loads (3 per o) are issued before any consumption: 6 independent
// uint4 loads in flight per lane = 2x the MLP of the round-0 kernel.
// __launch_bounds__(256,6): ~84 VGPR budget so the 6 loads + 16 accs stay live
// without spills (the fused kernel's VGPR=28 starvation is the anti-pattern).
__global__ __launch_bounds__(256, 6) void gather_bf16_v3_kernel(
    const unsigned short* __restrict__ xT,  // (N_IN, 32) bf16
    const float* __restrict__ w,            // (N_OUT, 3)
    const int*   __restrict__ idx,          // (N_OUT, 3)
    float* __restrict__ out)                // (B, N_OUT)
{
    const int t = threadIdx.x;
    const int g = t >> 2;                   // group 0..63
    const int l = t & 3;                    // 16B chunk within 64B row
    const int base0 = blockIdx.x * 128;
    const int oa = base0 + g;
    const int ob = base0 + 64 + g;
    if (oa >= N_OUT) return;
    const bool has_b = (ob < N_OUT);

    // ---- scalar streams (same address across the 4 group lanes -> broadcast)
    const int ba = 3 * oa;
    const int   ia0 = __builtin_nontemporal_load(idx + ba + 0);
    const int   ia1 = __builtin_nontemporal_load(idx + ba + 1);
    const int   ia2 = __builtin_nontemporal_load(idx + ba + 2);
    const float wa0 = __builtin_nontemporal_load(w + ba + 0);
    const float wa1 = __builtin_nontemporal_load(w + ba + 1);
    const float wa2 = __builtin_nontemporal_load(w + ba + 2);

    int   ib0 = 0, ib1 = 0, ib2 = 0;
    float wb0 = 0.f, wb1 = 0.f, wb2 = 0.f;
    if (has_b) {
        const int bb = 3 * ob;
        ib0 = __builtin_nontemporal_load(idx + bb + 0);
        ib1 = __builtin_nontemporal_load(idx + bb + 1);
        ib2 = __builtin_nontemporal_load(idx + bb + 2);
        wb0 = __builtin_nontemporal_load(w + bb + 0);
        wb1 = __builtin_nontemporal_load(w + bb + 1);
        wb2 = __builtin_nontemporal_load(w + bb + 2);
    }

    // ---- issue all 6 indexed row loads up front (lane l's 16B of each 64B row)
    const uint4 va0 = *(const uint4*)(xT + (size_t)ia0 * B_DIM + l * 8);
    const uint4 va1 = *(const uint4*)(xT + (size_t)ia1 * B_DIM + l * 8);
    const uint4 va2 = *(const uint4*)(xT + (size_t)ia2 * B_DIM + l * 8);
    const uint4 vb0 = *(const uint4*)(xT + (size_t)ib0 * B_DIM + l * 8);
    const uint4 vb1 = *(const uint4*)(xT + (size_t)ib1 * B_DIM + l * 8);
    const uint4 vb2 = *(const uint4*)(xT + (size_t)ib2 * B_DIM + l * 8);

    float acca[8], accb[8];
#pragma unroll
    for (int j = 0; j < 8; ++j) { acca[j] = 0.0f; accb[j] = 0.0f; }

    const unsigned int ua0[4] = {va0.x, va0.y, va0.z, va0.w};
    const unsigned int ua1[4] = {va1.x, va1.y, va1.z, va1.w};
    const unsigned int ua2[4] = {va2.x, va2.y, va2.z, va2.w};
    const unsigned int ub0[4] = {vb0.x, vb0.y, vb0.z, vb0.w};
    const unsigned int ub1[4] = {vb1.x, vb1.y, vb1.z, vb1.w};
    const unsigned int ub2[4] = {vb2.x, vb2.y, vb2.z, vb2.w};
#pragma unroll
    for (int m = 0; m < 4; ++m) {
        float a = acca[2 * m], c = acca[2 * m + 1];
        a = fmaf(wa0, __uint_as_float(ua0[m] << 16), a);
        c = fmaf(wa0, __uint_as_float(ua0[m] & 0xffff0000u), c);
        a = fmaf(wa1, __uint_as_float(ua1[m] << 16), a);
        c = fmaf(wa1, __uint_as_float(ua1[m] & 0xffff0000u), c);
        a = fmaf(wa2, __uint_as_float(ua2[m] << 16), a);
        c = fmaf(wa2, __uint_as_float(ua2[m] & 0xffff0000u), c);
        acca[2 * m] = a; acca[2 * m + 1] = c;

        float d = accb[2 * m], e = accb[2 * m + 1];
        d = fmaf(wb0, __uint_as_float(ub0[m] << 16), d);
        e = fmaf(wb0, __uint_as_float(ub0[m] & 0xffff0000u), e);
        d = fmaf(wb1, __uint_as_float(ub1[m] << 16), d);
        e = fmaf(wb1, __uint_as_float(ub1[m] & 0xffff0000u), e);
        d = fmaf(wb2, __uint_as_float(ub2[m] << 16), d);
        e = fmaf(wb2, __uint_as_float(ub2[m] & 0xffff0000u), e);
        accb[2 * m] = d; accb[2 * m + 1] = e;
    }

    // lane l owns b = 8l..8l+7; per store inst: 4 rows x 64B segments, coalesced
    float* obase_a = out + (size_t)(8 * l) * N_OUT + oa;
#pragma unroll
    for (int j = 0; j < 8; ++j) {
        __builtin_nontemporal_store(acca[j], obase_a + (size_t)j * N_OUT);
    }
    if (has_b) {
        float* obase_b = out + (size_t)(8 * l) * N_OUT + ob;
#pragma unroll
        for (int j = 0; j < 8; ++j) {
            __builtin_nontemporal_store(accb[j], obase_b + (size_t)j * N_OUT);
        }
    }
}

// ---------- Fallback (ws too small): direct fp32 gather ----------
__global__ __launch_bounds__(256) void direct_kernel(
    const float* __restrict__ x,
    const float* __restrict__ w,
    const int*   __restrict__ idx,
    float* __restrict__ out)
{
    const int o = blockIdx.x * blockDim.x + threadIdx.x;
    if (o >= N_OUT) return;
    const int base = 3 * o;
    const int i0 = idx[base + 0], i1 = idx[base + 1], i2 = idx[base + 2];
    const float w0 = w[base + 0], w1 = w[base + 1], w2 = w[base + 2];
#pragma unroll 4
    for (int b = 0; b < B_DIM; ++b) {
        const float* __restrict__ xr = x + (size_t)b * N_IN;
        float acc = w0 * xr[i0];
        acc = fmaf(w1, xr[i1], acc);
        acc = fmaf(w2, xr[i2], acc);
        out[(size_t)b * N_OUT + o] = acc;
    }
}

extern "C" void kernel_launch(void* const* d_in, const int* in_sizes, int n_in,
                              void* d_out, int out_size, void* d_ws, size_t ws_size,
                              hipStream_t stream) {
    const float* x   = (const float*)d_in[0];
    const float* w   = (const float*)d_in[1];
    const int*   idx = (const int*)d_in[2];
    float* out = (float*)d_out;

    const size_t xt_bytes = (size_t)N_IN * B_DIM * sizeof(unsigned short); // 64 MB

    if (ws_size >= xt_bytes) {
        unsigned short* xT = (unsigned short*)d_ws;
        transpose_bf16_kernel<<<N_IN / 64, 256, 0, stream>>>(x, xT);
        const int blocks = (N_OUT + 127) / 128;   // 128 o's per block (2 per group)
        gather_bf16_v3_kernel<<<blocks, 256, 0, stream>>>(xT, w, idx, out);
    } else {
        const int blocks = (N_OUT + 255) / 256;
        direct_kernel<<<blocks, 256, 0, stream>>>(x, w, idx, out);
    }
}